// Round 2
// baseline (1377.468 us; speedup 1.0000x reference)
//
#include <hip/hip_runtime.h>
#include <cstdint>

#define NB   4      // batches
#define NPT  8192   // points
#define NC   256    // feature channels
#define NS   1024   // FPS samples
#define NK   64     // neighbors per ball
#define PPT  8      // points per thread in FPS (8192 / 1024 threads)

// ---------------------------------------------------------------------------
// Kernel 1: farthest point sampling. One 1024-thread block per batch.
// Each thread keeps its 8 points (xyz) and running min_d in registers.
// Argmax via packed u64 key: (float_bits(min_d) << 32) | (0xFFFFFFFF - idx).
// Max of key == max value, ties broken toward SMALLEST index (numpy argmax
// first-occurrence semantics).
// NOTE: non-FMA left-to-right arithmetic here is VERIFIED bit-exact vs the
// reference (Output 0 passed in round 1). Do not "optimize" into FMA.
// ---------------------------------------------------------------------------
__global__ __launch_bounds__(1024) void fps_kernel(
    const float* __restrict__ xyz, float* __restrict__ sample_xyz)
{
    const int b   = blockIdx.x;
    const int tid = threadIdx.x;
    __shared__ unsigned long long red[16];
    __shared__ unsigned long long winner_s;

    const float* base = xyz + (size_t)b * NPT * 3;

    float px[PPT], py[PPT], pz[PPT], md[PPT];
#pragma unroll
    for (int i = 0; i < PPT; ++i) {
        const int idx = tid * PPT + i;
        px[i] = base[idx * 3 + 0];
        py[i] = base[idx * 3 + 1];
        pz[i] = base[idx * 3 + 2];
        md[i] = __builtin_inff();
    }

    int cur = 0;   // deterministic start at index 0 (matches reference)
    for (int s = 0; s < NS; ++s) {
        // broadcast-read the current centroid (wave-uniform address, L2 hit)
        const float sx = base[cur * 3 + 0];
        const float sy = base[cur * 3 + 1];
        const float sz = base[cur * 3 + 2];
        if (tid == 0) {
            float* o = sample_xyz + ((size_t)b * NS + s) * 3;
            o[0] = sx; o[1] = sy; o[2] = sz;
        }

        // update min_d for this thread's 8 points; track local best (max)
        unsigned long long best = 0ull;
#pragma unroll
        for (int i = 0; i < PPT; ++i) {
            // EXACT reference arithmetic: ((dx*dx + dy*dy) + dz*dz), no FMA
            const float dx = __fsub_rn(px[i], sx);
            const float dy = __fsub_rn(py[i], sy);
            const float dz = __fsub_rn(pz[i], sz);
            const float d  = __fadd_rn(
                __fadd_rn(__fmul_rn(dx, dx), __fmul_rn(dy, dy)),
                __fmul_rn(dz, dz));
            const float m = fminf(md[i], d);
            md[i] = m;
            const unsigned long long key =
                ((unsigned long long)__float_as_uint(m) << 32)
                | (unsigned long long)(0xFFFFFFFFu - (unsigned)(tid * PPT + i));
            if (key > best) best = key;
        }

        // wave (64-lane) max-reduce of packed key
#pragma unroll
        for (int msk = 1; msk < 64; msk <<= 1) {
            const unsigned long long o = __shfl_xor(best, msk, 64);
            if (o > best) best = o;
        }
        if ((tid & 63) == 0) red[tid >> 6] = best;
        __syncthreads();
        if (tid < 16) {
            unsigned long long v = red[tid];
#pragma unroll
            for (int msk = 1; msk < 16; msk <<= 1) {
                const unsigned long long o = __shfl_xor(v, msk, 64);
                if (o > v) v = o;
            }
            if (tid == 0) winner_s = v;
        }
        __syncthreads();
        cur = (int)(0xFFFFFFFFu - (unsigned)(winner_s & 0xFFFFFFFFull));
    }
}

// ---------------------------------------------------------------------------
// Kernel 2: ball query (first-64 in-radius indices, ascending) + feature
// gather. One 256-thread block per (b, s) centroid. Early-exit scan.
// d2 = na + nb - 2*dot; dot is an FMA CHAIN (XLA dot_general matmul-emitter
// semantics: t=mul(a0,b0); t=fma(a1,b1,t); t=fma(a2,b2,t)), while na/nb are
// non-FMA square-sums (XLA reduce semantics, verified via FPS passing).
// ---------------------------------------------------------------------------
__global__ __launch_bounds__(256) void bq_gather_kernel(
    const float* __restrict__ xyz, const float* __restrict__ feat,
    const float* __restrict__ sample_xyz, float* __restrict__ out_feat)
{
    const int s   = blockIdx.x;
    const int b   = blockIdx.y;
    const int tid = threadIdx.x;

    __shared__ int   list[NK];
    __shared__ int   wavecnt[4];
    __shared__ float cen[3];

    if (tid < 3) cen[tid] = sample_xyz[((size_t)b * NS + s) * 3 + tid];
    __syncthreads();
    const float sx = cen[0], sy = cen[1], sz = cen[2];
    // na = ((sx*sx + sy*sy) + sz*sz), non-FMA (reduce semantics)
    const float na = __fadd_rn(
        __fadd_rn(__fmul_rn(sx, sx), __fmul_rn(sy, sy)), __fmul_rn(sz, sz));
    const float* bxyz = xyz + (size_t)b * NPT * 3;

    int len = 0;
    for (int c0 = 0; c0 < NPT; c0 += 256) {
        const int idx = c0 + tid;
        const float x = bxyz[idx * 3 + 0];
        const float y = bxyz[idx * 3 + 1];
        const float z = bxyz[idx * 3 + 2];
        const float nb = __fadd_rn(
            __fadd_rn(__fmul_rn(x, x), __fmul_rn(y, y)), __fmul_rn(z, z));
        // dot as FMA chain (dot_general / matmul emitter semantics)
        const float dt = __fmaf_rn(sz, z, __fmaf_rn(sy, y, __fmul_rn(sx, x)));
        const float d2 = __fsub_rn(__fadd_rn(na, nb), __fmul_rn(2.0f, dt));
        const bool within = d2 < 0.04f;   // f32(0.2*0.2), weak-type promotion

        const unsigned long long m = __ballot(within);
        const int wv   = tid >> 6;
        const int lane = tid & 63;
        if (lane == 0) wavecnt[wv] = __popcll(m);
        __syncthreads();
        const int w0 = wavecnt[0], w1 = wavecnt[1], w2 = wavecnt[2], w3 = wavecnt[3];
        int off = len;
        if (wv > 0) off += w0;
        if (wv > 1) off += w1;
        if (wv > 2) off += w2;
        const int pre = __popcll(m & ((1ull << lane) - 1ull));
        const int pos = off + pre;
        if (within && pos < NK) list[pos] = idx;
        len += w0 + w1 + w2 + w3;
        __syncthreads();   // also orders list[] writes before gather reads
        if (len >= NK) break;
    }
    const int llen = len < NK ? len : NK;

    // gather: one wave per neighbor row (256 floats = 64 lanes x float4)
    const int lane = tid & 63;
    const int sub  = tid >> 6;   // 4 rows in flight per pass
    const float4* fbase = (const float4*)(feat + (size_t)b * NPT * NC);
    float4* obase = (float4*)(out_feat + (((size_t)b * NS + s) * (size_t)NK) * NC);
#pragma unroll
    for (int p = 0; p < NK / 4; ++p) {
        const int k   = p * 4 + sub;
        const int row = (k < llen) ? list[k] : NS;   // pad -> feat row 1024
        const float4 v = fbase[(size_t)row * (NC / 4) + lane];
        obase[(size_t)k * (NC / 4) + lane] = v;
    }
}

extern "C" void kernel_launch(void* const* d_in, const int* in_sizes, int n_in,
                              void* d_out, int out_size, void* d_ws, size_t ws_size,
                              hipStream_t stream) {
    const float* xyz  = (const float*)d_in[0];
    const float* feat = (const float*)d_in[1];
    float* out        = (float*)d_out;
    float* sample_xyz = out;                          // (B,S,3) = 12288 floats
    float* out_feat   = out + (size_t)NB * NS * 3;    // (B,S,K,C)

    fps_kernel<<<dim3(NB), dim3(1024), 0, stream>>>(xyz, sample_xyz);
    bq_gather_kernel<<<dim3(NS, NB), dim3(256), 0, stream>>>(
        xyz, feat, sample_xyz, out_feat);
}

// Round 3
// 1174.892 us; speedup vs baseline: 1.1724x; 1.1724x over previous
//
#include <hip/hip_runtime.h>
#include <cstdint>

#define NB   4      // batches
#define NPT  8192   // points
#define NC   256    // feature channels
#define NS   1024   // FPS samples
#define NK   64     // neighbors per ball
#define PPT  8      // points per thread in FPS (8192 / 1024 threads)

// ---------------------------------------------------------------------------
// DPP wave64 max-reduce (f32, all values >= 0 so +0 is a safe identity).
// Canonical LLVM atomic-optimizer pattern; result valid in lane 63.
// ---------------------------------------------------------------------------
template <int CTRL, int RMASK>
__device__ __forceinline__ float dpp_max_step(float x) {
    const int t = __builtin_amdgcn_update_dpp(
        0, __float_as_int(x), CTRL, RMASK, 0xf, false);
    return fmaxf(x, __int_as_float(t));
}
__device__ __forceinline__ float wave_max_f32(float x) {
    x = dpp_max_step<0x111, 0xf>(x);  // row_shr:1
    x = dpp_max_step<0x112, 0xf>(x);  // row_shr:2
    x = dpp_max_step<0x114, 0xf>(x);  // row_shr:4
    x = dpp_max_step<0x118, 0xf>(x);  // row_shr:8
    x = dpp_max_step<0x142, 0xa>(x);  // row_bcast:15 -> rows 1,3
    x = dpp_max_step<0x143, 0xc>(x);  // row_bcast:31 -> rows 2,3
    return x;                          // lane 63 holds wave max
}

// ---------------------------------------------------------------------------
// Kernel 1: farthest point sampling. One 1024-thread block per batch.
// Latency-optimized: DPP wave reduce (VALU pipe, no LDS round-trips),
// single barrier per step (red[] double-buffered by parity), centroid xyz
// re-fetched from an LDS SoA copy instead of global.
// Argmax semantics: numpy first-occurrence. Per-thread strict-> keeps the
// smallest achieving index; lanes/waves own ascending contiguous index
// blocks, so lowest achieving lane (ballot+ffs) = first occurrence; cross-
// wave ties broken by packed key (valbits<<32)|(0xFFFFFFFF-idx), max-reduced.
// NOTE: non-FMA left-to-right distance arithmetic is VERIFIED bit-exact vs
// the reference (round 1/2). Do not "optimize" into FMA.
// ---------------------------------------------------------------------------
__global__ __launch_bounds__(1024) void fps_kernel(
    const float* __restrict__ xyz, float* __restrict__ sample_xyz)
{
    const int b   = blockIdx.x;
    const int tid = threadIdx.x;

    __shared__ float Xs[NPT], Ys[NPT], Zs[NPT];        // 96 KB SoA copy
    __shared__ unsigned long long red[2][16];          // double-buffered keys

    const float* base = xyz + (size_t)b * NPT * 3;

    float px[PPT], py[PPT], pz[PPT], md[PPT];
#pragma unroll
    for (int i = 0; i < PPT; ++i) {
        const int p = tid * PPT + i;
        px[i] = base[p * 3 + 0];
        py[i] = base[p * 3 + 1];
        pz[i] = base[p * 3 + 2];
        md[i] = __builtin_inff();
        Xs[p] = px[i];  Ys[p] = py[i];  Zs[p] = pz[i];
    }
    __syncthreads();

    int widx = 0;   // deterministic start at index 0 (matches reference)
    for (int s = 0; s < NS; ++s) {
        // centroid xyz: uniform-address LDS broadcast reads
        const float sx = Xs[widx];
        const float sy = Ys[widx];
        const float sz = Zs[widx];
        if (tid == 0) {
            float* o = sample_xyz + ((size_t)b * NS + s) * 3;
            o[0] = sx; o[1] = sy; o[2] = sz;
        }

        // update min_d for this thread's 8 points; track first-occurrence max
        float    bestval = -1.0f;
        unsigned bestidx = 0u;
#pragma unroll
        for (int i = 0; i < PPT; ++i) {
            // EXACT reference arithmetic: ((dx*dx + dy*dy) + dz*dz), no FMA
            const float dx = __fsub_rn(px[i], sx);
            const float dy = __fsub_rn(py[i], sy);
            const float dz = __fsub_rn(pz[i], sz);
            const float d  = __fadd_rn(
                __fadd_rn(__fmul_rn(dx, dx), __fmul_rn(dy, dy)),
                __fmul_rn(dz, dz));
            const float m = fminf(md[i], d);
            md[i] = m;
            if (m > bestval) { bestval = m; bestidx = (unsigned)(tid * PPT + i); }
        }

        // wave max via DPP (VALU pipe), then first achieving lane via ballot
        const float wmax = wave_max_f32(bestval);
        const float smax = __int_as_float(
            __builtin_amdgcn_readlane(__float_as_int(wmax), 63));
        const unsigned long long msk = __ballot(bestval == smax);
        const int wl = __ffsll((long long)msk) - 1;          // lowest lane
        const unsigned widx_w =
            (unsigned)__builtin_amdgcn_readlane((int)bestidx, wl);
        if ((tid & 63) == 0) {
            red[s & 1][tid >> 6] =
                ((unsigned long long)__float_as_uint(smax) << 32)
                | (unsigned long long)(0xFFFFFFFFu - widx_w);
        }
        __syncthreads();

        // every thread redundantly reduces the 16 wave keys (broadcast reads)
        const ulonglong2* rp = (const ulonglong2*)red[s & 1];
        unsigned long long best = 0ull;
#pragma unroll
        for (int i = 0; i < 8; ++i) {
            const ulonglong2 v = rp[i];
            if (v.x > best) best = v.x;
            if (v.y > best) best = v.y;
        }
        widx = (int)(0xFFFFFFFFu - (unsigned)(best & 0xFFFFFFFFull));
    }
}

// ---------------------------------------------------------------------------
// Kernel 2: ball query (first-64 in-radius indices, ascending) + feature
// gather. One 256-thread block per (b, s) centroid. Early-exit scan.
// d2 = na + nb - 2*dot; dot is an FMA CHAIN (XLA dot_general semantics),
// na/nb are non-FMA square-sums (XLA reduce semantics). VERIFIED round 2.
// ---------------------------------------------------------------------------
__global__ __launch_bounds__(256) void bq_gather_kernel(
    const float* __restrict__ xyz, const float* __restrict__ feat,
    const float* __restrict__ sample_xyz, float* __restrict__ out_feat)
{
    const int s   = blockIdx.x;
    const int b   = blockIdx.y;
    const int tid = threadIdx.x;

    __shared__ int   list[NK];
    __shared__ int   wavecnt[4];
    __shared__ float cen[3];

    if (tid < 3) cen[tid] = sample_xyz[((size_t)b * NS + s) * 3 + tid];
    __syncthreads();
    const float sx = cen[0], sy = cen[1], sz = cen[2];
    const float na = __fadd_rn(
        __fadd_rn(__fmul_rn(sx, sx), __fmul_rn(sy, sy)), __fmul_rn(sz, sz));
    const float* bxyz = xyz + (size_t)b * NPT * 3;

    int len = 0;
    for (int c0 = 0; c0 < NPT; c0 += 256) {
        const int idx = c0 + tid;
        const float x = bxyz[idx * 3 + 0];
        const float y = bxyz[idx * 3 + 1];
        const float z = bxyz[idx * 3 + 2];
        const float nb = __fadd_rn(
            __fadd_rn(__fmul_rn(x, x), __fmul_rn(y, y)), __fmul_rn(z, z));
        // dot as FMA chain (dot_general / matmul emitter semantics)
        const float dt = __fmaf_rn(sz, z, __fmaf_rn(sy, y, __fmul_rn(sx, x)));
        const float d2 = __fsub_rn(__fadd_rn(na, nb), __fmul_rn(2.0f, dt));
        const bool within = d2 < 0.04f;   // f32(0.2*0.2)

        const unsigned long long m = __ballot(within);
        const int wv   = tid >> 6;
        const int lane = tid & 63;
        if (lane == 0) wavecnt[wv] = __popcll(m);
        __syncthreads();
        const int w0 = wavecnt[0], w1 = wavecnt[1], w2 = wavecnt[2], w3 = wavecnt[3];
        int off = len;
        if (wv > 0) off += w0;
        if (wv > 1) off += w1;
        if (wv > 2) off += w2;
        const int pre = __popcll(m & ((1ull << lane) - 1ull));
        const int pos = off + pre;
        if (within && pos < NK) list[pos] = idx;
        len += w0 + w1 + w2 + w3;
        __syncthreads();   // also orders list[] writes before gather reads
        if (len >= NK) break;
    }
    const int llen = len < NK ? len : NK;

    // gather: one wave per neighbor row (256 floats = 64 lanes x float4)
    const int lane = tid & 63;
    const int sub  = tid >> 6;   // 4 rows in flight per pass
    const float4* fbase = (const float4*)(feat + (size_t)b * NPT * NC);
    float4* obase = (float4*)(out_feat + (((size_t)b * NS + s) * (size_t)NK) * NC);
#pragma unroll
    for (int p = 0; p < NK / 4; ++p) {
        const int k   = p * 4 + sub;
        const int row = (k < llen) ? list[k] : NS;   // pad -> feat row 1024
        const float4 v = fbase[(size_t)row * (NC / 4) + lane];
        obase[(size_t)k * (NC / 4) + lane] = v;
    }
}

extern "C" void kernel_launch(void* const* d_in, const int* in_sizes, int n_in,
                              void* d_out, int out_size, void* d_ws, size_t ws_size,
                              hipStream_t stream) {
    const float* xyz  = (const float*)d_in[0];
    const float* feat = (const float*)d_in[1];
    float* out        = (float*)d_out;
    float* sample_xyz = out;                          // (B,S,3) = 12288 floats
    float* out_feat   = out + (size_t)NB * NS * 3;    // (B,S,K,C)

    fps_kernel<<<dim3(NB), dim3(1024), 0, stream>>>(xyz, sample_xyz);
    bq_gather_kernel<<<dim3(NS, NB), dim3(256), 0, stream>>>(
        xyz, feat, sample_xyz, out_feat);
}

// Round 4
// 971.219 us; speedup vs baseline: 1.4183x; 1.2097x over previous
//
#include <hip/hip_runtime.h>
#include <cstdint>

#define NB   4      // batches
#define NPT  8192   // points
#define NC   256    // feature channels
#define NS   1024   // FPS samples
#define NK   64     // neighbors per ball
#define FPT  16     // points per thread in FPS (8192 / 512 threads)

typedef float v2f __attribute__((ext_vector_type(2)));

// ---------------------------------------------------------------------------
// DPP wave64 max-reduce (f32, all values >= 0 so +0 is a safe identity).
// Canonical LLVM atomic-optimizer pattern; result valid in lane 63.
// ---------------------------------------------------------------------------
template <int CTRL, int RMASK>
__device__ __forceinline__ float dpp_max_step(float x) {
    const int t = __builtin_amdgcn_update_dpp(
        0, __float_as_int(x), CTRL, RMASK, 0xf, false);
    return fmaxf(x, __int_as_float(t));
}
__device__ __forceinline__ float wave_max_f32(float x) {
    x = dpp_max_step<0x111, 0xf>(x);  // row_shr:1
    x = dpp_max_step<0x112, 0xf>(x);  // row_shr:2
    x = dpp_max_step<0x114, 0xf>(x);  // row_shr:4
    x = dpp_max_step<0x118, 0xf>(x);  // row_shr:8
    x = dpp_max_step<0x142, 0xa>(x);  // row_bcast:15 -> rows 1,3
    x = dpp_max_step<0x143, 0xc>(x);  // row_bcast:31 -> rows 2,3
    return x;                          // lane 63 holds wave max
}

// ---------------------------------------------------------------------------
// Kernel 1: farthest point sampling. One 512-thread block (8 waves) per batch.
// VALU-issue-optimized: distance core runs on packed-FP32 (v_pk_* VOP3P) via
// <2 x float> vectors — per-element IEEE f32, bit-identical to scalar; fp
// contract(off) preserves the verified no-FMA ordering.
// First-occurrence argmax: lane's 16 points split x-half = tid*16+0..7,
// y-half = tid*16+8..15; strict-> per half keeps the earliest index; halves
// combined preferring x (all x indices < all y indices). Lanes/waves own
// ascending contiguous blocks, so lowest achieving lane (ballot+ffs) = first
// occurrence; cross-wave via packed key (valbits<<32)|(0xFFFFFFFF-idx).
// NOTE: non-FMA left-to-right distance arithmetic is VERIFIED bit-exact vs
// the reference (rounds 1-3). Do not "optimize" into FMA.
// ---------------------------------------------------------------------------
__global__ __launch_bounds__(512) void fps_kernel(
    const float* __restrict__ xyz, float* __restrict__ sample_xyz)
{
    const int b   = blockIdx.x;
    const int tid = threadIdx.x;

    __shared__ float Xs[NPT], Ys[NPT], Zs[NPT];        // 96 KB SoA copy
    __shared__ unsigned long long red[2][8];           // double-buffered keys

    const float* base = xyz + (size_t)b * NPT * 3;

    v2f px[8], py[8], pz[8], md[8];
#pragma unroll
    for (int j = 0; j < 8; ++j) {
        const int pa = tid * FPT + j;        // x-half point
        const int pb = tid * FPT + 8 + j;    // y-half point
        const float ax = base[pa * 3 + 0], ay = base[pa * 3 + 1], az = base[pa * 3 + 2];
        const float bx = base[pb * 3 + 0], by = base[pb * 3 + 1], bz = base[pb * 3 + 2];
        px[j] = (v2f){ax, bx};
        py[j] = (v2f){ay, by};
        pz[j] = (v2f){az, bz};
        md[j] = (v2f){__builtin_inff(), __builtin_inff()};
        Xs[pa] = ax; Ys[pa] = ay; Zs[pa] = az;
        Xs[pb] = bx; Ys[pb] = by; Zs[pb] = bz;
    }
    __syncthreads();

    int widx = 0;   // deterministic start at index 0 (matches reference)
    for (int s = 0; s < NS; ++s) {
        // centroid xyz: uniform-address LDS broadcast reads
        const float sx = Xs[widx];
        const float sy = Ys[widx];
        const float sz = Zs[widx];
        if (tid == 0) {
            float* o = sample_xyz + ((size_t)b * NS + s) * 3;
            o[0] = sx; o[1] = sy; o[2] = sz;
        }

        const v2f sxv = (v2f){sx, sx};
        const v2f syv = (v2f){sy, sy};
        const v2f szv = (v2f){sz, sz};

        v2f best2 = (v2f){-1.0f, -1.0f};
        int jx = 0, jy = 0;
        {
#pragma clang fp contract(off)
#pragma unroll
            for (int j = 0; j < 8; ++j) {
                // EXACT reference arithmetic per element:
                // ((dx*dx + dy*dy) + dz*dz), no FMA (contract off)
                const v2f dx = px[j] - sxv;
                const v2f dy = py[j] - syv;
                const v2f dz = pz[j] - szv;
                const v2f d  = (dx * dx + dy * dy) + dz * dz;
                const v2f m  = __builtin_elementwise_min(md[j], d);
                md[j] = m;
                // strict > keeps first occurrence within each half
                if (m.x > best2.x) jx = j;
                if (m.y > best2.y) jy = j;
                best2 = __builtin_elementwise_max(best2, m);
            }
        }
        // combine halves: every x-half index < every y-half index
        float    bestval;
        unsigned bestidx;
        if (best2.y > best2.x) { bestval = best2.y; bestidx = (unsigned)(tid * FPT + 8 + jy); }
        else                   { bestval = best2.x; bestidx = (unsigned)(tid * FPT + jx); }

        // wave max via DPP (VALU pipe), then first achieving lane via ballot
        const float wmax = wave_max_f32(bestval);
        const float smax = __int_as_float(
            __builtin_amdgcn_readlane(__float_as_int(wmax), 63));
        const unsigned long long msk = __ballot(bestval == smax);
        const int wl = __ffsll((long long)msk) - 1;          // lowest lane
        const unsigned widx_w =
            (unsigned)__builtin_amdgcn_readlane((int)bestidx, wl);
        if ((tid & 63) == 0) {
            red[s & 1][tid >> 6] =
                ((unsigned long long)__float_as_uint(smax) << 32)
                | (unsigned long long)(0xFFFFFFFFu - widx_w);
        }
        __syncthreads();

        // every thread redundantly reduces the 8 wave keys (broadcast reads)
        const ulonglong2* rp = (const ulonglong2*)red[s & 1];
        unsigned long long best = 0ull;
#pragma unroll
        for (int i = 0; i < 4; ++i) {
            const ulonglong2 v = rp[i];
            if (v.x > best) best = v.x;
            if (v.y > best) best = v.y;
        }
        widx = (int)(0xFFFFFFFFu - (unsigned)(best & 0xFFFFFFFFull));
    }
}

// ---------------------------------------------------------------------------
// Kernel 2: ball query (first-64 in-radius indices, ascending) + feature
// gather. One 256-thread block per (b, s) centroid. Early-exit scan.
// d2 = na + nb - 2*dot; dot is an FMA CHAIN (XLA dot_general semantics),
// na/nb are non-FMA square-sums (XLA reduce semantics). VERIFIED rounds 2-3.
// ---------------------------------------------------------------------------
__global__ __launch_bounds__(256) void bq_gather_kernel(
    const float* __restrict__ xyz, const float* __restrict__ feat,
    const float* __restrict__ sample_xyz, float* __restrict__ out_feat)
{
    const int s   = blockIdx.x;
    const int b   = blockIdx.y;
    const int tid = threadIdx.x;

    __shared__ int   list[NK];
    __shared__ int   wavecnt[4];
    __shared__ float cen[3];

    if (tid < 3) cen[tid] = sample_xyz[((size_t)b * NS + s) * 3 + tid];
    __syncthreads();
    const float sx = cen[0], sy = cen[1], sz = cen[2];
    const float na = __fadd_rn(
        __fadd_rn(__fmul_rn(sx, sx), __fmul_rn(sy, sy)), __fmul_rn(sz, sz));
    const float* bxyz = xyz + (size_t)b * NPT * 3;

    int len = 0;
    for (int c0 = 0; c0 < NPT; c0 += 256) {
        const int idx = c0 + tid;
        const float x = bxyz[idx * 3 + 0];
        const float y = bxyz[idx * 3 + 1];
        const float z = bxyz[idx * 3 + 2];
        const float nb = __fadd_rn(
            __fadd_rn(__fmul_rn(x, x), __fmul_rn(y, y)), __fmul_rn(z, z));
        // dot as FMA chain (dot_general / matmul emitter semantics)
        const float dt = __fmaf_rn(sz, z, __fmaf_rn(sy, y, __fmul_rn(sx, x)));
        const float d2 = __fsub_rn(__fadd_rn(na, nb), __fmul_rn(2.0f, dt));
        const bool within = d2 < 0.04f;   // f32(0.2*0.2)

        const unsigned long long m = __ballot(within);
        const int wv   = tid >> 6;
        const int lane = tid & 63;
        if (lane == 0) wavecnt[wv] = __popcll(m);
        __syncthreads();
        const int w0 = wavecnt[0], w1 = wavecnt[1], w2 = wavecnt[2], w3 = wavecnt[3];
        int off = len;
        if (wv > 0) off += w0;
        if (wv > 1) off += w1;
        if (wv > 2) off += w2;
        const int pre = __popcll(m & ((1ull << lane) - 1ull));
        const int pos = off + pre;
        if (within && pos < NK) list[pos] = idx;
        len += w0 + w1 + w2 + w3;
        __syncthreads();   // also orders list[] writes before gather reads
        if (len >= NK) break;
    }
    const int llen = len < NK ? len : NK;

    // gather: one wave per neighbor row (256 floats = 64 lanes x float4)
    const int lane = tid & 63;
    const int sub  = tid >> 6;   // 4 rows in flight per pass
    const float4* fbase = (const float4*)(feat + (size_t)b * NPT * NC);
    float4* obase = (float4*)(out_feat + (((size_t)b * NS + s) * (size_t)NK) * NC);
#pragma unroll
    for (int p = 0; p < NK / 4; ++p) {
        const int k   = p * 4 + sub;
        const int row = (k < llen) ? list[k] : NS;   // pad -> feat row 1024
        const float4 v = fbase[(size_t)row * (NC / 4) + lane];
        obase[(size_t)k * (NC / 4) + lane] = v;
    }
}

extern "C" void kernel_launch(void* const* d_in, const int* in_sizes, int n_in,
                              void* d_out, int out_size, void* d_ws, size_t ws_size,
                              hipStream_t stream) {
    const float* xyz  = (const float*)d_in[0];
    const float* feat = (const float*)d_in[1];
    float* out        = (float*)d_out;
    float* sample_xyz = out;                          // (B,S,3) = 12288 floats
    float* out_feat   = out + (size_t)NB * NS * 3;    // (B,S,K,C)

    fps_kernel<<<dim3(NB), dim3(512), 0, stream>>>(xyz, sample_xyz);
    bq_gather_kernel<<<dim3(NS, NB), dim3(256), 0, stream>>>(
        xyz, feat, sample_xyz, out_feat);
}

// Round 5
// 886.660 us; speedup vs baseline: 1.5535x; 1.0954x over previous
//
#include <hip/hip_runtime.h>
#include <cstdint>

#define NB   4      // batches
#define NPT  8192   // points
#define NC   256    // feature channels
#define NS   1024   // FPS samples
#define NK   64     // neighbors per ball
#define FPT  16     // points per thread in FPS (8192 / 512 threads)

typedef float v2f __attribute__((ext_vector_type(2)));

// ---------------------------------------------------------------------------
// DPP wave64 max-reduce (f32, all values >= 0 so +0 is a safe identity).
// Canonical LLVM atomic-optimizer pattern; result valid in lane 63.
// ---------------------------------------------------------------------------
template <int CTRL, int RMASK>
__device__ __forceinline__ float dpp_max_step(float x) {
    const int t = __builtin_amdgcn_update_dpp(
        0, __float_as_int(x), CTRL, RMASK, 0xf, false);
    return fmaxf(x, __int_as_float(t));
}
__device__ __forceinline__ float wave_max_f32(float x) {
    x = dpp_max_step<0x111, 0xf>(x);  // row_shr:1
    x = dpp_max_step<0x112, 0xf>(x);  // row_shr:2
    x = dpp_max_step<0x114, 0xf>(x);  // row_shr:4
    x = dpp_max_step<0x118, 0xf>(x);  // row_shr:8
    x = dpp_max_step<0x142, 0xa>(x);  // row_bcast:15 -> rows 1,3
    x = dpp_max_step<0x143, 0xc>(x);  // row_bcast:31 -> rows 2,3
    return x;                          // lane 63 holds wave max
}

// ---------------------------------------------------------------------------
// Kernel 1: farthest point sampling. One 512-thread block (8 waves) per batch.
// Serial-loop hygiene: NO global memory ops inside the 1024-step loop.
//  - sample_xyz accumulated in LDS, flushed coalesced at the end.
//  - cross-wave winner via LDS atomicMax(u64) into a 3-slot rotating buffer;
//    post-barrier is a single broadcast ds_read_b64.
//    3-slot zeroing proof: slot[nxt] (= slot used at step s+1) was last READ
//    at step s-2's post-barrier phase, which happens-before barrier(s-1),
//    which happens-before tid0's zeroing at step s pre-barrier; the zero is
//    ordered before step s+1's atomics by barrier(s). No race.
// First-occurrence argmax: lane's 16 points split x-half = tid*16+0..7,
// y-half = tid*16+8..15; strict-> per half keeps the earliest index; halves
// combined preferring x (all x indices < all y indices). Lanes/waves own
// ascending contiguous blocks, so lowest achieving lane (ballot+ffs) = first
// occurrence; cross-wave via packed key (valbits<<32)|(0xFFFFFFFF-idx).
// NOTE: non-FMA left-to-right distance arithmetic (contract off) is VERIFIED
// bit-exact vs the reference (rounds 1-4). Do not "optimize" into FMA.
// ---------------------------------------------------------------------------
__global__ __launch_bounds__(512) void fps_kernel(
    const float* __restrict__ xyz, float* __restrict__ sample_xyz)
{
    const int b   = blockIdx.x;
    const int tid = threadIdx.x;

    __shared__ float Xs[NPT], Ys[NPT], Zs[NPT];        // 96 KB SoA copy
    __shared__ float Samp[NS * 3];                     // 12 KB result buffer
    __shared__ unsigned long long slots[3];            // rotating winner slots

    const float* base = xyz + (size_t)b * NPT * 3;

    v2f px[8], py[8], pz[8], md[8];
#pragma unroll
    for (int j = 0; j < 8; ++j) {
        const int pa = tid * FPT + j;        // x-half point
        const int pb = tid * FPT + 8 + j;    // y-half point
        const float ax = base[pa * 3 + 0], ay = base[pa * 3 + 1], az = base[pa * 3 + 2];
        const float bx = base[pb * 3 + 0], by = base[pb * 3 + 1], bz = base[pb * 3 + 2];
        px[j] = (v2f){ax, bx};
        py[j] = (v2f){ay, by};
        pz[j] = (v2f){az, bz};
        md[j] = (v2f){__builtin_inff(), __builtin_inff()};
        Xs[pa] = ax; Ys[pa] = ay; Zs[pa] = az;
        Xs[pb] = bx; Ys[pb] = by; Zs[pb] = bz;
    }
    if (tid < 3) slots[tid] = 0ull;
    __syncthreads();

    int widx = 0;           // deterministic start at index 0 (matches reference)
    int cur = 0, nxt = 1;   // rotating slot indices (avoid % in the loop)
    for (int s = 0; s < NS; ++s) {
        // centroid xyz: uniform-address LDS broadcast reads
        const float sx = Xs[widx];
        const float sy = Ys[widx];
        const float sz = Zs[widx];
        if (tid == 0) {
            Samp[s * 3 + 0] = sx; Samp[s * 3 + 1] = sy; Samp[s * 3 + 2] = sz;
            slots[nxt] = 0ull;   // safe per 3-slot proof above
        }

        const v2f sxv = (v2f){sx, sx};
        const v2f syv = (v2f){sy, sy};
        const v2f szv = (v2f){sz, sz};

        v2f best2 = (v2f){-1.0f, -1.0f};
        int jx = 0, jy = 0;
        {
#pragma clang fp contract(off)
#pragma unroll
            for (int j = 0; j < 8; ++j) {
                // EXACT reference arithmetic per element:
                // ((dx*dx + dy*dy) + dz*dz), no FMA (contract off)
                const v2f dx = px[j] - sxv;
                const v2f dy = py[j] - syv;
                const v2f dz = pz[j] - szv;
                const v2f d  = (dx * dx + dy * dy) + dz * dz;
                const v2f m  = __builtin_elementwise_min(md[j], d);
                md[j] = m;
                // strict > keeps first occurrence within each half
                if (m.x > best2.x) jx = j;
                if (m.y > best2.y) jy = j;
                best2 = __builtin_elementwise_max(best2, m);
            }
        }
        // combine halves: every x-half index < every y-half index
        float    bestval;
        unsigned bestidx;
        if (best2.y > best2.x) { bestval = best2.y; bestidx = (unsigned)(tid * FPT + 8 + jy); }
        else                   { bestval = best2.x; bestidx = (unsigned)(tid * FPT + jx); }

        // wave max via DPP (VALU pipe), then first achieving lane via ballot
        const float wmax = wave_max_f32(bestval);
        const float smax = __int_as_float(
            __builtin_amdgcn_readlane(__float_as_int(wmax), 63));
        const unsigned long long msk = __ballot(bestval == smax);
        const int wl = __ffsll((long long)msk) - 1;          // lowest lane
        const unsigned widx_w =
            (unsigned)__builtin_amdgcn_readlane((int)bestidx, wl);
        if ((tid & 63) == 0) {
            const unsigned long long key =
                ((unsigned long long)__float_as_uint(smax) << 32)
                | (unsigned long long)(0xFFFFFFFFu - widx_w);
            atomicMax(&slots[cur], key);     // ds_max_u64, fire-and-forget
        }
        __syncthreads();

        // broadcast read of the winning key
        const unsigned long long best = slots[cur];
        widx = (int)(0xFFFFFFFFu - (unsigned)(best & 0xFFFFFFFFull));
        cur = nxt;
        nxt = (nxt == 2) ? 0 : nxt + 1;
    }

    // coalesced flush of the sample buffer (visible: written pre-barrier of
    // each step; last in-loop __syncthreads orders it)
    float* o = sample_xyz + (size_t)b * NS * 3;
    for (int i = tid; i < NS * 3; i += 512) o[i] = Samp[i];
}

// ---------------------------------------------------------------------------
// Kernel 2: ball query (first-64 in-radius indices, ascending) + feature
// gather. One 256-thread block per (b, s) centroid. Early-exit scan.
// d2 = na + nb - 2*dot; dot is an FMA CHAIN (XLA dot_general semantics),
// na/nb are non-FMA square-sums (XLA reduce semantics). VERIFIED rounds 2-4.
// ---------------------------------------------------------------------------
__global__ __launch_bounds__(256) void bq_gather_kernel(
    const float* __restrict__ xyz, const float* __restrict__ feat,
    const float* __restrict__ sample_xyz, float* __restrict__ out_feat)
{
    const int s   = blockIdx.x;
    const int b   = blockIdx.y;
    const int tid = threadIdx.x;

    __shared__ int   list[NK];
    __shared__ int   wavecnt[4];
    __shared__ float cen[3];

    if (tid < 3) cen[tid] = sample_xyz[((size_t)b * NS + s) * 3 + tid];
    __syncthreads();
    const float sx = cen[0], sy = cen[1], sz = cen[2];
    const float na = __fadd_rn(
        __fadd_rn(__fmul_rn(sx, sx), __fmul_rn(sy, sy)), __fmul_rn(sz, sz));
    const float* bxyz = xyz + (size_t)b * NPT * 3;

    int len = 0;
    for (int c0 = 0; c0 < NPT; c0 += 256) {
        const int idx = c0 + tid;
        const float x = bxyz[idx * 3 + 0];
        const float y = bxyz[idx * 3 + 1];
        const float z = bxyz[idx * 3 + 2];
        const float nb = __fadd_rn(
            __fadd_rn(__fmul_rn(x, x), __fmul_rn(y, y)), __fmul_rn(z, z));
        // dot as FMA chain (dot_general / matmul emitter semantics)
        const float dt = __fmaf_rn(sz, z, __fmaf_rn(sy, y, __fmul_rn(sx, x)));
        const float d2 = __fsub_rn(__fadd_rn(na, nb), __fmul_rn(2.0f, dt));
        const bool within = d2 < 0.04f;   // f32(0.2*0.2)

        const unsigned long long m = __ballot(within);
        const int wv   = tid >> 6;
        const int lane = tid & 63;
        if (lane == 0) wavecnt[wv] = __popcll(m);
        __syncthreads();
        const int w0 = wavecnt[0], w1 = wavecnt[1], w2 = wavecnt[2], w3 = wavecnt[3];
        int off = len;
        if (wv > 0) off += w0;
        if (wv > 1) off += w1;
        if (wv > 2) off += w2;
        const int pre = __popcll(m & ((1ull << lane) - 1ull));
        const int pos = off + pre;
        if (within && pos < NK) list[pos] = idx;
        len += w0 + w1 + w2 + w3;
        __syncthreads();   // also orders list[] writes before gather reads
        if (len >= NK) break;
    }
    const int llen = len < NK ? len : NK;

    // gather: one wave per neighbor row (256 floats = 64 lanes x float4)
    const int lane = tid & 63;
    const int sub  = tid >> 6;   // 4 rows in flight per pass
    const float4* fbase = (const float4*)(feat + (size_t)b * NPT * NC);
    float4* obase = (float4*)(out_feat + (((size_t)b * NS + s) * (size_t)NK) * NC);
#pragma unroll
    for (int p = 0; p < NK / 4; ++p) {
        const int k   = p * 4 + sub;
        const int row = (k < llen) ? list[k] : NS;   // pad -> feat row 1024
        const float4 v = fbase[(size_t)row * (NC / 4) + lane];
        obase[(size_t)k * (NC / 4) + lane] = v;
    }
}

extern "C" void kernel_launch(void* const* d_in, const int* in_sizes, int n_in,
                              void* d_out, int out_size, void* d_ws, size_t ws_size,
                              hipStream_t stream) {
    const float* xyz  = (const float*)d_in[0];
    const float* feat = (const float*)d_in[1];
    float* out        = (float*)d_out;
    float* sample_xyz = out;                          // (B,S,3) = 12288 floats
    float* out_feat   = out + (size_t)NB * NS * 3;    // (B,S,K,C)

    fps_kernel<<<dim3(NB), dim3(512), 0, stream>>>(xyz, sample_xyz);
    bq_gather_kernel<<<dim3(NS, NB), dim3(256), 0, stream>>>(
        xyz, feat, sample_xyz, out_feat);
}